// Round 8
// baseline (251.502 us; speedup 1.0000x reference)
//
#include <hip/hip_runtime.h>
#include <stdint.h>

#define TOKENS 8192
#define EDIM 512
#define HNUM 8
#define RNUM 16
#define DDIM 64
#define KDIM 512

typedef short v8s __attribute__((ext_vector_type(8)));
typedef float v4f __attribute__((ext_vector_type(4)));
typedef float v16f __attribute__((ext_vector_type(16)));

__device__ inline float b2f(unsigned short u) {
    union { unsigned int i; float f; } c; c.i = ((unsigned int)u) << 16; return c.f;
}
__device__ inline unsigned short f2b(float f) {
    union { float f; unsigned int i; } c; c.f = f;
    unsigned int i = c.i + 0x7fffu + ((c.i >> 16) & 1u);
    return (unsigned short)(i >> 16);
}

// async global->LDS, 16B per lane; LDS dest = wave-uniform base + lane*16
#define GLD16(dst, src) \
    __builtin_amdgcn_global_load_lds((__attribute__((address_space(1))) void*)(src), \
                                     (__attribute__((address_space(3))) void*)(dst), 16, 0, 0)

// ---- fp32 -> bf16 convert, 5 segments in one launch (blockIdx.y picks) ----
__global__ __launch_bounds__(256)
void cvt5(const float* __restrict__ s0, const float* __restrict__ s1,
          const float* __restrict__ s2, const float* __restrict__ s3,
          const float* __restrict__ s4,
          unsigned short* __restrict__ d0, unsigned short* __restrict__ d1,
          unsigned short* __restrict__ d2, unsigned short* __restrict__ d3,
          unsigned short* __restrict__ d4,
          int n0, int n1, int n2, int n3, int n4)
{
    const float* s; unsigned short* d; int n;
    switch (blockIdx.y) {
        case 0: s = s0; d = d0; n = n0; break;
        case 1: s = s1; d = d1; n = n1; break;
        case 2: s = s2; d = d2; n = n2; break;
        case 3: s = s3; d = d3; n = n3; break;
        default: s = s4; d = d4; n = n4; break;
    }
    size_t base = (size_t)blockIdx.x * 2048 + (size_t)threadIdx.x * 8;
    if (base >= (size_t)n) return;
    const float4* sp = (const float4*)(s + base);
    float4 f0 = sp[0], f1 = sp[1];
    v8s o;
    o[0] = (short)f2b(f0.x); o[1] = (short)f2b(f0.y);
    o[2] = (short)f2b(f0.z); o[3] = (short)f2b(f0.w);
    o[4] = (short)f2b(f1.x); o[5] = (short)f2b(f1.y);
    o[6] = (short)f2b(f1.z); o[7] = (short)f2b(f1.w);
    *(v8s*)(d + base) = o;
}

// ---- small-GEMM path: 64x64 tiles, 1024 blocks -> 4 blocks/CU ----
// (round-5 proven config: faster than 128x128/256-block variants at this size)
// MODE 0: outH = bf16((C + bias[n]) * 0.125)   (Q projection)
// MODE 2: outF = C + bias[n]                   (O projection)
template <int MODE>
__global__ __launch_bounds__(256, 4)
void gemm64(const unsigned short* __restrict__ A,
            const unsigned short* __restrict__ B,
            const float* __restrict__ bias,
            float* __restrict__ outF,
            unsigned short* __restrict__ outH)
{
    __shared__ unsigned short As[64 * 32];
    __shared__ unsigned short Bs[64 * 32];

    const int tid  = threadIdx.x;
    const int w    = tid >> 6;
    const int lane = tid & 63;
    const int quad = lane >> 4;
    const int l16  = lane & 15;
    const int wm   = w >> 1, wn = w & 1;
    const int m0   = blockIdx.x * 64;
    const int n0   = blockIdx.y * 64;

    v4f acc[2][2];
#pragma unroll
    for (int i = 0; i < 2; ++i)
#pragma unroll
        for (int j = 0; j < 2; ++j)
            acc[i][j] = (v4f){0.f, 0.f, 0.f, 0.f};

    for (int kt = 0; kt < KDIM / 32; ++kt) {
        int c = w * 64 + lane;
        const unsigned short* sa = A + (size_t)(m0 + (c >> 2)) * KDIM + kt * 32 + (c & 3) * 8;
        GLD16(&As[w * 512], sa);
        const unsigned short* sb = B + (size_t)(n0 + (c >> 2)) * KDIM + kt * 32 + (c & 3) * 8;
        GLD16(&Bs[w * 512], sb);
        __syncthreads();

        v8s af[2], bf[2];
#pragma unroll
        for (int mt = 0; mt < 2; ++mt)
            af[mt] = *(const v8s*)&As[(wm * 32 + mt * 16 + l16) * 32 + quad * 8];
#pragma unroll
        for (int nt = 0; nt < 2; ++nt)
            bf[nt] = *(const v8s*)&Bs[(wn * 32 + nt * 16 + l16) * 32 + quad * 8];
#pragma unroll
        for (int mt = 0; mt < 2; ++mt)
#pragma unroll
            for (int nt = 0; nt < 2; ++nt)
                acc[mt][nt] = __builtin_amdgcn_mfma_f32_16x16x32_bf16(af[mt], bf[nt], acc[mt][nt], 0, 0, 0);
        __syncthreads();
    }

#pragma unroll
    for (int mt = 0; mt < 2; ++mt)
#pragma unroll
        for (int nt = 0; nt < 2; ++nt) {
            int col = n0 + wn * 32 + nt * 16 + l16;
            float bb = bias[col];
#pragma unroll
            for (int rg = 0; rg < 4; ++rg) {
                int row = m0 + wm * 32 + mt * 16 + quad * 4 + rg;
                float v = acc[mt][nt][rg] + bb;
                if (MODE == 0) outH[(size_t)row * EDIM + col] = f2b(v * 0.125f);
                else           outF[(size_t)row * EDIM + col] = v;
            }
        }
}

// ============================================================================
// V-GEMM, 256x256x(BK=64), R3's proven 2-seg schedule (best: 83.0 us),
// made PERSISTENT over 4 n-tiles (fill amortized) and upgraded to
// v_mfma_f32_32x32x16_bf16 (half the MFMA instruction count, -17% pipe time).
//   Per K-epoch T (cur = T&1, ob = cur^1), R3's staging-hazard discipline:
//    S0: read A-half0 frags (8 b128) + all B frags (8 b128, kept in regs)
//        stage (T+1).A1 -> ob, (T+1).B0 -> ob   [ob: no alias with cur reads]
//        MFMA mq0 (16x 32x32), mid-BARRIER
//    S1: read A-half1 frags (8); B reused from regs
//        stage (T+2).A0 -> cur [A0 reads done pre-barrier],
//              (T+2).B1 -> cur [B1 read in S0]
//        MFMA mq1 (16), WAITV(4) [T<30; else 0], BARRIER
//   32x32 fragment reads under the g^(row&7) swizzle: 8-lane groups cover
//   8 consecutive rows at fixed granule -> all 8 slots -> conflict-free
//   (round-4/5 validated 8-lane-group model).
//   C-layout (HW-verified m74/m101): col=lane&31, row=(reg&3)+8*(reg>>2)+4*hi.
//   Rule contraction: lane holds rules {0-3,8-11}+4hi for 2 d's; one
//   shfl_xor(32) merges the complementary rule half. Scrambled out1 store
//   unchanged.
// ============================================================================
__device__ __forceinline__ v8s ldfrag(const unsigned short* base, int r, int g) {
    return *(const v8s*)(base + (r << 6) + ((g ^ (r & 7)) << 3));
}

#define MEMBAR asm volatile("" ::: "memory")
#define BARX do { MEMBAR; __builtin_amdgcn_s_barrier(); MEMBAR; } while (0)
#define BARL do { MEMBAR; asm volatile("s_waitcnt lgkmcnt(0)" ::: "memory"); \
                  __builtin_amdgcn_s_barrier(); MEMBAR; } while (0)
#define WAITV(n) asm volatile("s_waitcnt vmcnt(" #n ")" ::: "memory")

// stage one 128x64 half-tile: wave w covers rows (half*128 + w*16 .. +15);
// source pre-swizzled so linear GLD16 dest realizes slot = g ^ (row&7).
#define STAGE_H(ldsArr, bufi, half_, gptr, rowbase, kof) do { \
    const unsigned short* s_ = (gptr) + (size_t)((rowbase) + (half_) * 128 + (w << 4) + rsub) * KDIM \
                               + (kof) + (gsw << 3); \
    GLD16(&ldsArr[bufi][(half_) * 8192 + (w << 10)], s_); \
    GLD16(&ldsArr[bufi][(half_) * 8192 + (w << 10) + 512], s_ + 8 * KDIM); \
} while (0)

__global__ __launch_bounds__(512, 2)
void gemm_v(const unsigned short* __restrict__ A,
            const unsigned short* __restrict__ B,
            const float* __restrict__ bias,
            unsigned short* __restrict__ outH,
            const float* __restrict__ attn)
{
    __shared__ unsigned short As[2][16384];
    __shared__ unsigned short Bs[2][16384];
    __shared__ unsigned short Os[4096];

    const int tid  = threadIdx.x;
    const int w    = tid >> 6;          // wave 0..7
    const int lane = tid & 63;
    const int l31  = lane & 31;
    const int hi   = lane >> 5;         // k-half / row-offset selector
    const int wm   = w >> 2;            // 0..1
    const int wn   = w & 3;             // 0..3
    const int rsub = lane >> 3;         // staging row-in-chunk
    const int gsw  = (lane & 7) ^ rsub; // pre-swizzled source k-granule

    // XCD map (round-5): grid 256 = 32 mb x 8 ng; XCD cell 8mb x 4ng
    const int c  = blockIdx.x & 7;
    const int j  = blockIdx.x >> 3;            // 0..31
    const int mb = ((c & 3) << 3) | (j & 7);   // 0..31
    const int ng = ((c >> 2) << 2) | (j >> 3); // 0..7
    const int m0  = mb << 8;
    const int n0b = ng << 10;                  // 4 n-tiles x 256 tokens

    v16f acc[2][2][2];                  // [mq][mi][nq]
#pragma unroll
    for (int mq = 0; mq < 2; ++mq)
#pragma unroll
        for (int mi = 0; mi < 2; ++mi)
#pragma unroll
            for (int nq = 0; nq < 2; ++nq)
#pragma unroll
                for (int e = 0; e < 16; ++e)
                    acc[mq][mi][nq][e] = 0.f;

    const int h  = m0 >> 10;
    const int d0 = (m0 >> 4) & 63;

    // ---- prologue: tile 0 fully, then (1).A0, (1).B1 ----
    STAGE_H(As, 0, 0, A, m0, 0);
    STAGE_H(Bs, 0, 0, B, n0b, 0);
    STAGE_H(As, 0, 1, A, m0, 0);
    STAGE_H(Bs, 0, 1, B, n0b, 0);
    STAGE_H(As, 1, 0, A, m0, 64);
    STAGE_H(Bs, 1, 1, B, n0b, 64);
    WAITV(4);                           // tile 0 landed; 2 half-tiles in flight
    BARX;

#pragma unroll 1
    for (int nt = 0; nt < 4; ++nt) {
        const int n0t = n0b + (nt << 8);
#pragma unroll
        for (int T8 = 0; T8 < 8; ++T8) {
            const int T   = nt * 8 + T8;
            const int cur = T8 & 1, ob = cur ^ 1;
            const unsigned short* abase = &As[cur][0];
            const unsigned short* bbase = &Bs[cur][0];
            const int t1 = T + 1, t2 = T + 2;

            v8s af[2][4], bf[2][4];     // af[mi][kt]; bf[nq][kt]

            // ---- S0: A-half0 + all B reads, stage (t1).A1/(t1).B0 -> ob ----
#pragma unroll
            for (int mi = 0; mi < 2; ++mi)
#pragma unroll
                for (int kt = 0; kt < 4; ++kt)
                    af[mi][kt] = ldfrag(abase, wm * 64 + mi * 32 + l31, kt * 2 + hi);
#pragma unroll
            for (int nq = 0; nq < 2; ++nq)
#pragma unroll
                for (int kt = 0; kt < 4; ++kt)
                    bf[nq][kt] = ldfrag(bbase, nq * 128 + wn * 32 + l31, kt * 2 + hi);
            if (t1 < 32) {
                const int kof1 = (t1 & 7) << 6;
                STAGE_H(As, ob, 1, A, m0, kof1);
                STAGE_H(Bs, ob, 0, B, n0b + ((t1 >> 3) << 8), kof1);
            }
            __builtin_amdgcn_s_setprio(1);
#pragma unroll
            for (int kt = 0; kt < 4; ++kt)
#pragma unroll
                for (int mi = 0; mi < 2; ++mi)
#pragma unroll
                    for (int nq = 0; nq < 2; ++nq)
                        acc[0][mi][nq] = __builtin_amdgcn_mfma_f32_32x32x16_bf16(
                            af[mi][kt], bf[nq][kt], acc[0][mi][nq], 0, 0, 0);
            __builtin_amdgcn_s_setprio(0);
            BARX;

            // ---- S1: A-half1 reads, B reused; stage (t2).A0/(t2).B1 -> cur ----
#pragma unroll
            for (int mi = 0; mi < 2; ++mi)
#pragma unroll
                for (int kt = 0; kt < 4; ++kt)
                    af[mi][kt] = ldfrag(abase, 128 + wm * 64 + mi * 32 + l31, kt * 2 + hi);
            if (t2 < 32) {
                const int kof2 = (t2 & 7) << 6;
                STAGE_H(As, cur, 0, A, m0, kof2);
                STAGE_H(Bs, cur, 1, B, n0b + ((t2 >> 3) << 8), kof2);
            }
            __builtin_amdgcn_s_setprio(1);
#pragma unroll
            for (int kt = 0; kt < 4; ++kt)
#pragma unroll
                for (int mi = 0; mi < 2; ++mi)
#pragma unroll
                    for (int nq = 0; nq < 2; ++nq)
                        acc[1][mi][nq] = __builtin_amdgcn_mfma_f32_32x32x16_bf16(
                            af[mi][kt], bf[nq][kt], acc[1][mi][nq], 0, 0, 0);
            __builtin_amdgcn_s_setprio(0);
            if (T < 30) { WAITV(4); } else { WAITV(0); }
            BARX;
        }

        // ---- per-tile epilogue: rule contraction + scrambled out1 store ----
#pragma unroll
        for (int mq = 0; mq < 2; ++mq)
#pragma unroll
            for (int mi = 0; mi < 2; ++mi) {
                const int mbase = m0 + mq * 128 + wm * 64 + mi * 32;
                float4 b40 = *(const float4*)&bias[mbase + 0  + hi * 4];
                float4 b41 = *(const float4*)&bias[mbase + 8  + hi * 4];
                float4 b42 = *(const float4*)&bias[mbase + 16 + hi * 4];
                float4 b43 = *(const float4*)&bias[mbase + 24 + hi * 4];
#pragma unroll
                for (int nq = 0; nq < 2; ++nq) {
                    const int tloc = nq * 128 + wn * 32 + l31;
                    const size_t t = (size_t)(n0t + tloc);
                    float4 alo = *(const float4*)&attn[t * (HNUM * RNUM) + h * RNUM + hi * 4];
                    float4 ahi = *(const float4*)&attn[t * (HNUM * RNUM) + h * RNUM + 8 + hi * 4];
                    v16f a = acc[mq][mi][nq];
                    float v0 = (a[0]  + b40.x) * alo.x + (a[1]  + b40.y) * alo.y
                             + (a[2]  + b40.z) * alo.z + (a[3]  + b40.w) * alo.w
                             + (a[4]  + b41.x) * ahi.x + (a[5]  + b41.y) * ahi.y
                             + (a[6]  + b41.z) * ahi.z + (a[7]  + b41.w) * ahi.w;
                    float v1 = (a[8]  + b42.x) * alo.x + (a[9]  + b42.y) * alo.y
                             + (a[10] + b42.z) * alo.z + (a[11] + b42.w) * alo.w
                             + (a[12] + b43.x) * ahi.x + (a[13] + b43.y) * ahi.y
                             + (a[14] + b43.z) * ahi.z + (a[15] + b43.w) * ahi.w;
                    v0 += __shfl_xor(v0, 32);
                    v1 += __shfl_xor(v1, 32);
                    if (hi == 0) {
                        const int dl = mq * 8 + wm * 4 + mi * 2;
                        Os[tloc * 16 + dl]     = f2b(v0 * 0.125f);
                        Os[tloc * 16 + dl + 1] = f2b(v1 * 0.125f);
                    }
                }
            }
        BARL;   // lgkm-only barrier: in-flight prefetch survives
        {
            int tl = tid >> 1, hf = tid & 1;
            int sg = n0t + tl;
            int g  = (sg >> 11) * 2048 + h * 256 + ((sg & 2047) >> 3);
            int jx = (sg & 7) * 64 + d0 + hf * 8;
            *(v8s*)&outH[(size_t)g * EDIM + jx] = *(const v8s*)&Os[tl * 16 + hf * 8];
        }
        if (nt < 3) {
#pragma unroll
            for (int mq = 0; mq < 2; ++mq)
#pragma unroll
                for (int mi = 0; mi < 2; ++mi)
#pragma unroll
                    for (int nq = 0; nq < 2; ++nq)
#pragma unroll
                        for (int e = 0; e < 16; ++e)
                            acc[mq][mi][nq][e] = 0.f;
        }
    }
}

// per (token, head): z_r = -0.5*mean_d(((q-k)/w)^2), softmax over 16 rules.
// grid (TOKENS/16, HNUM), block 256 = 16 tokens x 16 rules.
#define RST 72   // padded LDS row stride (floats)
__global__ __launch_bounds__(256)
void rules_softmax(const unsigned short* __restrict__ q,  // bf16 (8192 x 512)
                   const float* __restrict__ rk,
                   const float* __restrict__ rw,
                   float* __restrict__ attn)
{
    __shared__ float ql[16 * RST];
    __shared__ float rkl[16 * RST];
    __shared__ float iwl[16 * RST];
    const int h   = blockIdx.y;
    const int t0  = blockIdx.x * 16;
    const int tid = threadIdx.x;

#pragma unroll
    for (int i = 0; i < 4; ++i) {
        int jj = tid + i * 256;
        int r = jj >> 6, d = jj & 63;
        rkl[r * RST + d] = rk[h * (RNUM * DDIM) + jj];
        float wv = rw[h * (RNUM * DDIM) + jj];
        iwl[r * RST + d] = 1.0f / (wv * wv);
    }
    {
        int jj = tid * 4;
        int row = jj >> 6, d = jj & 63;
        const unsigned short* src = q + (size_t)(t0 + row) * EDIM + h * DDIM + d;
        unsigned short u0 = src[0], u1 = src[1], u2 = src[2], u3 = src[3];
        ql[row * RST + d + 0] = b2f(u0);
        ql[row * RST + d + 1] = b2f(u1);
        ql[row * RST + d + 2] = b2f(u2);
        ql[row * RST + d + 3] = b2f(u3);
    }
    __syncthreads();

    const int tl = tid >> 4;
    const int r  = tid & 15;
    const float* qrow = &ql[tl * RST];
    const float* krow = &rkl[r * RST];
    const float* wrow = &iwl[r * RST];
    float z = 0.f;
#pragma unroll
    for (int d4 = 0; d4 < 16; ++d4) {
        float4 qv = *(const float4*)&qrow[d4 * 4];
        float4 kv = *(const float4*)&krow[d4 * 4];
        float4 wv = *(const float4*)&wrow[d4 * 4];
        float a0 = qv.x - kv.x; z += a0 * a0 * wv.x;
        float a1 = qv.y - kv.y; z += a1 * a1 * wv.y;
        float a2 = qv.z - kv.z; z += a2 * a2 * wv.z;
        float a3 = qv.w - kv.w; z += a3 * a3 * wv.w;
    }
    z *= (-0.5f / 64.f);
    float mx = z;
#pragma unroll
    for (int s = 1; s < 16; s <<= 1) mx = fmaxf(mx, __shfl_xor(mx, s));
    float e = __expf(z - mx);
    float sum = e;
#pragma unroll
    for (int s = 1; s < 16; s <<= 1) sum += __shfl_xor(sum, s);
    attn[(size_t)(t0 + tl) * (HNUM * RNUM) + h * RNUM + r] = e / sum;
}

extern "C" void kernel_launch(void* const* d_in, const int* in_sizes, int n_in,
                              void* d_out, int out_size, void* d_ws, size_t ws_size,
                              hipStream_t stream) {
    const float* query = (const float*)d_in[0];
    // d_in[1] = key (unused by the reference)
    const float* value = (const float*)d_in[2];
    const float* Wq = (const float*)d_in[3];
    const float* bq = (const float*)d_in[4];
    const float* Wv = (const float*)d_in[5];
    const float* bv = (const float*)d_in[6];
    const float* Wo = (const float*)d_in[7];
    const float* bo = (const float*)d_in[8];
    const float* rk = (const float*)d_in[9];
    const float* rw = (const float*)d_in[10];

    char* ws = (char*)d_ws;
    unsigned short* qbf  = (unsigned short*)(ws);                       //  8 MiB: query bf16
    unsigned short* vbf  = (unsigned short*)(ws + (size_t)( 8 << 20));  //  8 MiB: value bf16
    unsigned short* Wqb  = (unsigned short*)(ws + (size_t)(16 << 20));  // 0.5 MiB
    unsigned short* Wvb  = (unsigned short*)(ws + (size_t)(17 << 20));  //  8 MiB
    unsigned short* Wob  = (unsigned short*)(ws + (size_t)(25 << 20));  // 0.5 MiB
    unsigned short* out1 = (unsigned short*)(ws + (size_t)(26 << 20));  //  8 MiB: scrambled bf16
    unsigned short* qf   = (unsigned short*)(ws + (size_t)(34 << 20));  //  8 MiB: q bf16
    float* attn          = (float*)(ws + (size_t)(42 << 20));           //  4 MiB: attn fp32

    dim3 blk(256);
    // 0) fp32 -> bf16 conversions
    cvt5<<<dim3(2048, 5), blk, 0, stream>>>(query, value, Wv, Wq, Wo,
                                            qbf, vbf, Wvb, Wqb, Wob,
                                            TOKENS * EDIM, TOKENS * EDIM, EDIM * RNUM * EDIM,
                                            EDIM * EDIM, EDIM * EDIM);
    // 1) q = bf16((query @ Wq^T + bq) * D^-0.5)   [64x64 tiles, 1024 blocks]
    gemm64<0><<<dim3(TOKENS / 64, EDIM / 64), blk, 0, stream>>>(qbf, Wqb, bq, nullptr, qf);
    // 2) fuzzy rule attention weights
    rules_softmax<<<dim3(TOKENS / 16, HNUM), blk, 0, stream>>>(qf, rk, rw, attn);
    // 3) V-GEMM + rule contraction [256 persistent blocks, 32x32 MFMA]
    gemm_v<<<dim3(256), dim3(512), 0, stream>>>(Wvb, vbf, bv, out1, attn);
    // 4) final projection -> d_out (fp32)  [64x64 tiles, 1024 blocks]
    gemm64<2><<<dim3(TOKENS / 64, EDIM / 64), blk, 0, stream>>>(out1, Wob, bo, (float*)d_out, nullptr);
}